// Round 1
// baseline (188.168 us; speedup 1.0000x reference)
//
#include <hip/hip_runtime.h>

typedef unsigned short u16;
typedef unsigned int   u32;
typedef __attribute__((ext_vector_type(8))) short short8;   // 8 bf16 = 4 VGPRs (guide §3)
typedef __attribute__((ext_vector_type(4))) float f32x4;

#define NB    4      // batch
#define NCH   256    // channels
#define NHD   8      // heads
#define HD    32     // head dim
#define NSP   2304   // H*W
#define NBH   32     // NB*NHD

// round-to-nearest-even fp32 -> bf16 bits
__device__ __forceinline__ u16 f2bf(float f) {
    u32 u = __float_as_uint(f);
    u += 0x7FFFu + ((u >> 16) & 1u);
    return (u16)(u >> 16);
}
__device__ __forceinline__ u32 pack2(float a, float b) {
    return (u32)f2bf(a) | ((u32)f2bf(b) << 16);
}

// async global->LDS, 16B per lane; LDS dest = wave-uniform base + lane*16
#define GLOAD_LDS16(g, l) \
  __builtin_amdgcn_global_load_lds((const __attribute__((address_space(1))) void*)(g), \
                                   (__attribute__((address_space(3))) void*)(l), 16, 0, 0)

// ---------------- proj_w -> bf16 ----------------
__global__ __launch_bounds__(256) void wcast_kernel(const float* __restrict__ w,
                                                    u16* __restrict__ wb) {
    int i = blockIdx.x * 256 + threadIdx.x;          // 16384 float4 chunks
    float4 v = ((const float4*)w)[i];
    ((uint2*)wb)[i] = make_uint2(pack2(v.x, v.y), pack2(v.z, v.w));
}

// ---------------- normalize q,k; cast v (transposed layout is native) ----------------
__global__ __launch_bounds__(256) void prep_kernel(
    const float* __restrict__ qkv, u16* __restrict__ Qn,
    u16* __restrict__ Kn, u16* __restrict__ Vt)
{
    const int bh = blockIdx.y;
    const int b = bh >> 3, head = bh & 7;
    const int n = blockIdx.x * 256 + threadIdx.x;
    const float* qp = qkv + ((size_t)(b * 3 * NCH + head * HD)) * NSP + n;
    const float* kp = qp + (size_t)NCH * NSP;
    const float* vp = qp + (size_t)(2 * NCH) * NSP;

    float qv[HD], kv[HD];
    float qs = 0.f, ks = 0.f;
#pragma unroll
    for (int d = 0; d < HD; ++d) {
        qv[d] = qp[(size_t)d * NSP];
        kv[d] = kp[(size_t)d * NSP];
        qs += qv[d] * qv[d];
        ks += kv[d] * kv[d];
    }
    const float qsc = 1.f / fmaxf(sqrtf(qs), 1e-12f);
    const float ksc = 1.f / fmaxf(sqrtf(ks), 1e-12f);
    u32* qd = (u32*)(Qn + ((size_t)bh * NSP + n) * HD);
    u32* kd = (u32*)(Kn + ((size_t)bh * NSP + n) * HD);
#pragma unroll
    for (int i = 0; i < HD / 2; ++i) {
        qd[i] = pack2(qv[2 * i] * qsc, qv[2 * i + 1] * qsc);
        kd[i] = pack2(kv[2 * i] * ksc, kv[2 * i + 1] * ksc);
    }
    u16* vd = Vt + (size_t)bh * HD * NSP + n;
#pragma unroll
    for (int d = 0; d < HD; ++d)
        vd[(size_t)d * NSP] = f2bf(vp[(size_t)d * NSP]);
}

// ---------------- flash attention: exp(relu(QK^T*t)) / rowsum, O = P V ----------------
// block = 256 thr (4 waves), grid (NSP/64, NBH). Wave w owns 16 Q rows.
__global__ __launch_bounds__(256) void attn_kernel(
    const u16* __restrict__ Qn, const u16* __restrict__ Kn,
    const u16* __restrict__ Vt, const float* __restrict__ temp,
    u16* __restrict__ X)
{
    __shared__ u16 lds[8704];   // K 64x32 (2048) | Vt 32x64 (2048) | P 4 waves x 16x72 (4608)
    const int bh = blockIdx.y;
    const int b = bh >> 3, head = bh & 7;
    const int w = threadIdx.x >> 6, lane = threadIdx.x & 63;
    const int l15 = lane & 15, quad = lane >> 4;
    const int mbase = blockIdx.x * 64 + w * 16;
    // exp(relu(s*temp)) == exp2(relu(s*temp*log2e)) (log2e>0 preserves relu)
    const float tl2 = temp[head] * 1.44269504088896f;

    const u16* Kbh = Kn + (size_t)bh * NSP * HD;
    const u16* Vbh = Vt + (size_t)bh * HD * NSP;

    u16* Klds = lds;
    u16* Vlds = lds + 2048;
    u16* Plds = lds + 4096 + w * (16 * 72);   // row stride 72 (144B = 9*16B): aligned b128 reads

    // Q A-frag: A[m=lane&15][k=quad*8+j], held for whole kernel
    const short8 qfrag = *(const short8*)(Qn + ((size_t)bh * NSP + mbase + l15) * HD + quad * 8);

    f32x4 oacc0 = {0.f, 0.f, 0.f, 0.f};   // d cols 0..15
    f32x4 oacc1 = {0.f, 0.f, 0.f, 0.f};   // d cols 16..31
    float rs[4] = {0.f, 0.f, 0.f, 0.f};   // rowsum, rows quad*4+r

    for (int kt = 0; kt < NSP / 64; ++kt) {
        // stage K tile (64 rows x 32) contiguous, V^T tile (32 d x 64 n)
        GLOAD_LDS16(Kbh + (size_t)kt * 64 * HD + threadIdx.x * 8, Klds + w * 512);
        {
            const int d = threadIdx.x >> 3, c = threadIdx.x & 7;
            GLOAD_LDS16(Vbh + (size_t)d * NSP + kt * 64 + c * 8, Vlds + w * 512);
        }
        __syncthreads();   // drains vmcnt -> LDS valid

        // S = Q K^T : 4 col-tiles of 16
        f32x4 sf[4];
#pragma unroll
        for (int jn = 0; jn < 4; ++jn) {
            const short8 bf = *(const short8*)(Klds + (jn * 16 + l15) * HD + quad * 8);
            sf[jn] = __builtin_amdgcn_mfma_f32_16x16x32_bf16(qfrag, bf, (f32x4){0.f, 0.f, 0.f, 0.f}, 0, 0, 0);
        }
        // p = exp2(relu(s*tl2)); accumulate rowsum; write P (C/D layout -> row-major LDS)
#pragma unroll
        for (int jn = 0; jn < 4; ++jn) {
#pragma unroll
            for (int r = 0; r < 4; ++r) {
                float p = exp2f(fmaxf(sf[jn][r] * tl2, 0.f));
                rs[r] += p;
                Plds[(quad * 4 + r) * 72 + jn * 16 + l15] = f2bf(p);
            }
        }
        // O += P V : P as A-frag (16x32 k-chunks), V^T as B-frag
#pragma unroll
        for (int kc = 0; kc < 2; ++kc) {
            const short8 pa  = *(const short8*)(Plds + l15 * 72 + kc * 32 + quad * 8);
            const short8 vb0 = *(const short8*)(Vlds + (size_t)l15 * 64 + kc * 32 + quad * 8);
            const short8 vb1 = *(const short8*)(Vlds + (size_t)(16 + l15) * 64 + kc * 32 + quad * 8);
            oacc0 = __builtin_amdgcn_mfma_f32_16x16x32_bf16(pa, vb0, oacc0, 0, 0, 0);
            oacc1 = __builtin_amdgcn_mfma_f32_16x16x32_bf16(pa, vb1, oacc1, 0, 0, 0);
        }
        __syncthreads();   // protect K/V tiles before restage
    }

    // reduce rowsum across the 16 lanes of each quad
#pragma unroll
    for (int m = 1; m < 16; m <<= 1) {
#pragma unroll
        for (int r = 0; r < 4; ++r) rs[r] += __shfl_xor(rs[r], m, 64);
    }
    float inv[4];
#pragma unroll
    for (int r = 0; r < 4; ++r) inv[r] = 1.f / rs[r];

    // write X[b][n][head*32+d] bf16 for proj GEMM
    u16* Xb = X + (size_t)b * NSP * NCH + head * HD;
#pragma unroll
    for (int r = 0; r < 4; ++r) {
        u16* row = Xb + (size_t)(mbase + quad * 4 + r) * NCH;
        row[l15]      = f2bf(oacc0[r] * inv[r]);
        row[16 + l15] = f2bf(oacc1[r] * inv[r]);
    }
}

// ---------------- 1x1 conv: out[b,o,n] = sum_c W[o,c] X[b,n,c] + bias[o] ----------------
__global__ __launch_bounds__(256) void proj_kernel(
    const u16* __restrict__ Wb, const u16* __restrict__ X,
    const float* __restrict__ bias, float* __restrict__ out)
{
    const int b = blockIdx.z;
    const int w = threadIdx.x >> 6, lane = threadIdx.x & 63;
    const int l15 = lane & 15, quad = lane >> 4;
    const int obase = blockIdx.y * 64 + w * 16;
    const int nbase = blockIdx.x * 64;

    const u16* wrow = Wb + (size_t)(obase + l15) * NCH + quad * 8;
    const u16* xrow = X + ((size_t)b * NSP + nbase + l15) * NCH + quad * 8;

    f32x4 acc[4] = {{0,0,0,0},{0,0,0,0},{0,0,0,0},{0,0,0,0}};
#pragma unroll
    for (int ks = 0; ks < 8; ++ks) {
        const short8 af = *(const short8*)(wrow + ks * 32);
#pragma unroll
        for (int jn = 0; jn < 4; ++jn) {
            const short8 bf = *(const short8*)(xrow + (size_t)jn * 16 * NCH + ks * 32);
            acc[jn] = __builtin_amdgcn_mfma_f32_16x16x32_bf16(af, bf, acc[jn], 0, 0, 0);
        }
    }
#pragma unroll
    for (int r = 0; r < 4; ++r) {
        const int o = obase + quad * 4 + r;
        const float bo = bias[o];
        float* orow = out + ((size_t)b * NCH + o) * NSP + nbase;
#pragma unroll
        for (int jn = 0; jn < 4; ++jn)
            orow[jn * 16 + l15] = acc[jn][r] + bo;
    }
}

extern "C" void kernel_launch(void* const* d_in, const int* in_sizes, int n_in,
                              void* d_out, int out_size, void* d_ws, size_t ws_size,
                              hipStream_t stream) {
    const float* qkv   = (const float*)d_in[0];
    const float* temp  = (const float*)d_in[1];   // 8 head temps
    const float* projw = (const float*)d_in[2];
    const float* projb = (const float*)d_in[3];
    float* out = (float*)d_out;

    // workspace: Qn | Kn | Vt | X (each 2,359,296 bf16) | Wb (65,536 bf16)  ~19 MB
    u16* Qn = (u16*)d_ws;
    u16* Kn = Qn + (size_t)NBH * NSP * HD;
    u16* Vt = Kn + (size_t)NBH * NSP * HD;
    u16* X  = Vt + (size_t)NBH * NSP * HD;
    u16* Wb = X + (size_t)NB * NSP * NCH;

    wcast_kernel<<<dim3(64), dim3(256), 0, stream>>>(projw, Wb);
    prep_kernel<<<dim3(NSP / 256, NBH), dim3(256), 0, stream>>>(qkv, Qn, Kn, Vt);
    attn_kernel<<<dim3(NSP / 64, NBH), dim3(256), 0, stream>>>(Qn, Kn, Vt, temp, X);
    proj_kernel<<<dim3(NSP / 64, NCH / 64, NB), dim3(256), 0, stream>>>(Wb, X, projb, out);
}